// Round 5
// baseline (3371.976 us; speedup 1.0000x reference)
//
#include <hip/hip_runtime.h>

#define LL 128      // memory length
#define BB 16       // batch
#define HH 512      // hidden
#define VV 16000    // vocab
#define TT 32       // steps
#define NH 8        // heads
#define DK 64       // head dim
#define NBLK 250    // mega grid (co-resident: 1 block/CU on 256 CUs)

// workspace layout (float offsets)
#define WS_K 0
#define WS_V (LL*BB*HH)                     // K,V: rows l*BB+b, 512 cols
#define WS_CTXT (2*LL*BB*HH)                // ctx transposed [k][b] (512*16)
#define WS_HS0 (WS_CTXT + BB*HH)            // h ping [k][b]
#define WS_HS1 (WS_HS0 + BB*HH)             // h pong [k][b]
#define WS_P   (WS_HS1 + BB*HH)             // p[b][h][128]
#define WS_SLOTS_F (WS_P + BB*NH*LL)        // (TT+1)*BB u64 argmax slots
#define WS_BAR (WS_SLOTS_F + 2*(TT+1)*BB + 16)  // cnt, sense

#define OUT_HID_OFF ((size_t)TT*BB*VV)
#define OUT_SC_OFF  (OUT_HID_OFF + (size_t)TT*BB*HH)

// slots[t*BB+b]: hi32 = monotonic float encoding, lo32 = 0xFFFFFFFF - col
// atomicMax -> max value, tie -> smallest col (jnp.argmax first occurrence)

// ---------------- kv projection + per-call init ----------------
__global__ __launch_bounds__(256) void kv_kernel(const float* __restrict__ mem,
        const float* __restrict__ Wk, const float* __restrict__ bk,
        const float* __restrict__ Wv, const float* __restrict__ bv,
        float* __restrict__ ws) {
    int blk = blockIdx.x;
    int rg = blk >> 4, ct = blk & 15;
    int isV = ct >= 8;
    int colbase = (ct & 7) * 64;
    const float* W = isV ? Wv : Wk;
    const float* bias = isV ? bv : bk;
    float* outp = ws + (isV ? WS_V : WS_K);
    int rowbase = rg * 16;
    int tid = threadIdx.x;
    __shared__ float As[16*516];

    {   // stage 16x512 A rows into padded LDS
        const float4* srcp = (const float4*)(mem + (size_t)rowbase*512);
        #pragma unroll
        for (int j = 0; j < 8; ++j) {
            int i = tid + 256*j;
            float4 v = srcp[i];
            int row = i >> 7, c4i = i & 127;
            *(float4*)(As + row*516 + c4i*4) = v;
        }
    }
    if (blk == 0) {
        for (int i = tid; i < BB*HH; i += 256) ws[WS_HS0 + i] = 0.f;   // h(-1)=0
        unsigned long long* slots = (unsigned long long*)(ws + WS_SLOTS_F);
        for (int i = tid; i < (TT+1)*BB; i += 256)
            slots[i] = (i < BB) ? 0xFFFFFFFFull : 0ull;   // step0 argmax(zeros)=0
        if (tid == 0) *(unsigned*)(ws + WS_BAR) = 0u;     // barrier cnt = 0
    }
    __syncthreads();

    int cq = tid & 15;
    int rq4 = (tid >> 4) & 3;
    int kq = tid >> 6;
    float acc[4][4];
    #pragma unroll
    for (int i = 0; i < 4; ++i) { acc[i][0]=0.f; acc[i][1]=0.f; acc[i][2]=0.f; acc[i][3]=0.f; }
    const float* wp = W + colbase + cq*4;
    for (int k4 = kq*32; k4 < kq*32 + 32; ++k4) {
        float4 a0 = *(const float4*)(As + (rq4*4+0)*516 + k4*4);
        float4 a1 = *(const float4*)(As + (rq4*4+1)*516 + k4*4);
        float4 a2 = *(const float4*)(As + (rq4*4+2)*516 + k4*4);
        float4 a3 = *(const float4*)(As + (rq4*4+3)*516 + k4*4);
        const float* wrow = wp + (size_t)(4*k4)*512;
        float4 w0 = *(const float4*)(wrow);
        float4 w1 = *(const float4*)(wrow + 512);
        float4 w2 = *(const float4*)(wrow + 1024);
        float4 w3 = *(const float4*)(wrow + 1536);
        #define KV_FMA(ri, A) \
            acc[ri][0] += A.x*w0.x + A.y*w1.x + A.z*w2.x + A.w*w3.x; \
            acc[ri][1] += A.x*w0.y + A.y*w1.y + A.z*w2.y + A.w*w3.y; \
            acc[ri][2] += A.x*w0.z + A.y*w1.z + A.z*w2.z + A.w*w3.z; \
            acc[ri][3] += A.x*w0.w + A.y*w1.w + A.z*w2.w + A.w*w3.w;
        KV_FMA(0, a0) KV_FMA(1, a1) KV_FMA(2, a2) KV_FMA(3, a3)
        #undef KV_FMA
    }
    __syncthreads();
    float* red = As;
    #pragma unroll
    for (int ri = 0; ri < 4; ++ri)
        *(float4*)(red + ri*1024 + tid*4) =
            make_float4(acc[ri][0], acc[ri][1], acc[ri][2], acc[ri][3]);
    __syncthreads();
    {
        int c4 = tid & 15, row = tid >> 4;
        int rq = row >> 2, ri = row & 3;
        float4 b4v = *(const float4*)(bias + colbase + c4*4);
        float o[4] = {b4v.x, b4v.y, b4v.z, b4v.w};
        #pragma unroll
        for (int kq2 = 0; kq2 < 4; ++kq2) {
            const float* pr = red + ri*1024 + (kq2*64 + rq*16 + c4)*4;
            o[0] += pr[0]; o[1] += pr[1]; o[2] += pr[2]; o[3] += pr[3];
        }
        *(float4*)(outp + (size_t)(rowbase + row)*512 + colbase + c4*4) =
            make_float4(o[0], o[1], o[2], o[3]);
    }
}

// ---------------- grid barrier (sense-reversing, replay-safe) ----------------
__device__ __forceinline__ void gridbar(unsigned* cnt, unsigned* sense,
                                        unsigned target) {
    __syncthreads();
    if (threadIdx.x == 0) {
        __threadfence();                                   // release phase writes
        unsigned old = atomicAdd(cnt, 1u);
        if (old == (unsigned)NBLK - 1u) {
            __hip_atomic_store(cnt, 0u, __ATOMIC_RELAXED, __HIP_MEMORY_SCOPE_AGENT);
            __hip_atomic_fetch_add(sense, 1u, __ATOMIC_RELEASE, __HIP_MEMORY_SCOPE_AGENT);
        } else {
            while ((int)(__hip_atomic_load(sense, __ATOMIC_RELAXED,
                         __HIP_MEMORY_SCOPE_AGENT) - target) < 0)
                __builtin_amdgcn_s_sleep(8);
        }
        __threadfence();                                   // acquire before reads
    }
    __syncthreads();
}

// ---------------- mega kernel: all 32 steps ----------------
__global__ __launch_bounds__(512) void mega_kernel(
        const float* __restrict__ emb, const float* __restrict__ Wq,
        const float* __restrict__ bq,
        const float* __restrict__ Wih, const float* __restrict__ bih,
        const float* __restrict__ Whh, const float* __restrict__ bhh,
        const float* __restrict__ Wf,  const float* __restrict__ bf,
        const int* __restrict__ olen, float* __restrict__ ws,
        float* __restrict__ out) {
    __shared__ __align__(16) char s_raw[57344];   // 56 KB, aliased per phase
    int blk = blockIdx.x, tid = threadIdx.x;
    unsigned* cnt = (unsigned*)(ws + WS_BAR);
    unsigned* sense = cnt + 1;
    unsigned s0 = 0;
    if (tid == 0)
        s0 = __hip_atomic_load(sense, __ATOMIC_ACQUIRE, __HIP_MEMORY_SCOPE_AGENT);
    unsigned bno = 0;
    unsigned long long* slots = (unsigned long long*)(ws + WS_SLOTS_F);

    for (int t = 0; t < TT; ++t) {
        const float* hs_prev = ws + ((t & 1) ? WS_HS1 : WS_HS0);
        float* hs_new = ws + ((t & 1) ? WS_HS0 : WS_HS1);

        // ================= P1: attention (blocks 0..127) =================
        if (blk < 128) {
            int b = blk >> 3, h = blk & 7;
            float* q     = (float*)s_raw;                 // 1024
            float* part  = q + 1024;                      // 16*64
            float* qh    = part + 1024;                   // 64
            float* sp    = qh + 64;                       // 4*128
            float* p     = sp + 512;                      // 128
            float* cpart = p + 128;                       // 8*64

            unsigned long long slot = slots[t*BB + b];
            unsigned idx = 0xFFFFFFFFu - (unsigned)(slot & 0xFFFFFFFFull);
            q[tid] = emb[(size_t)idx*HH + tid];
            q[HH + tid] = hs_prev[tid*16 + b];
            __syncthreads();

            {   // qproj: c2 = tid&31 (2 cols), kc = tid>>5 (16 slices of 64 k)
                int c2 = tid & 31, kc = tid >> 5;
                const float* wp = Wq + (size_t)(kc*64)*HH + h*64 + c2*2;
                const float* qp = q + kc*64;
                float a0 = 0.f, a1 = 0.f;
                #pragma unroll 8
                for (int kk = 0; kk < 64; ++kk) {
                    float x = qp[kk];
                    float2 w2 = *(const float2*)(wp + (size_t)kk*HH);
                    a0 += x*w2.x; a1 += x*w2.y;
                }
                part[kc*64 + c2*2]     = a0;
                part[kc*64 + c2*2 + 1] = a1;
            }
            __syncthreads();
            if (tid < 64) {
                float s = bq[h*64 + tid];
                #pragma unroll
                for (int kc = 0; kc < 16; ++kc) s += part[kc*64 + tid];
                qh[tid] = s;
            }
            __syncthreads();

            {   // scores: l = tid&127, jh = tid>>7 (0..3, 16 k each)
                int l = tid & 127, jh = tid >> 7;
                const float4* kr = (const float4*)(ws + WS_K +
                                   ((size_t)(l*BB + b))*HH + h*DK) + jh*4;
                const float4* q4 = (const float4*)qh + jh*4;
                float acc = 0.f;
                #pragma unroll
                for (int j = 0; j < 4; ++j) {
                    float4 kv = kr[j], qq = q4[j];
                    acc += qq.x*kv.x + qq.y*kv.y + qq.z*kv.z + qq.w*kv.w;
                }
                sp[jh*128 + l] = acc;
            }
            __syncthreads();

            if (tid < 64) {   // softmax over 128 (wave 0)
                float s0v = (sp[tid]    + sp[128+tid]    + sp[256+tid]    + sp[384+tid])    * 0.125f;
                float s1v = (sp[64+tid] + sp[128+64+tid] + sp[256+64+tid] + sp[384+64+tid]) * 0.125f;
                float m = fmaxf(s0v, s1v);
                #pragma unroll
                for (int off = 32; off; off >>= 1) m = fmaxf(m, __shfl_xor(m, off));
                float e0 = __expf(s0v - m), e1 = __expf(s1v - m);
                float sum = e0 + e1;
                #pragma unroll
                for (int off = 32; off; off >>= 1) sum += __shfl_xor(sum, off);
                float inv = 1.f / sum;
                p[tid]      = e0 * inv;
                p[64 + tid] = e1 * inv;
            }
            __syncthreads();
            if (tid < 128) ws[WS_P + (size_t)(b*NH + h)*LL + tid] = p[tid];

            {   // ctx: c = tid&63, lc = tid>>6 (8 slices of 16 l)
                int c = tid & 63, lc = tid >> 6;
                const float* Vp = ws + WS_V + h*DK + c;
                float acc = 0.f;
                #pragma unroll 8
                for (int li = 0; li < 16; ++li) {
                    int l = lc*16 + li;
                    acc += p[l] * Vp[(size_t)(l*BB + b)*HH];
                }
                cpart[lc*64 + c] = acc;
            }
            __syncthreads();
            if (tid < 64) {
                float v = cpart[tid];
                #pragma unroll
                for (int lc = 1; lc < 8; ++lc) v += cpart[lc*64 + tid];
                ws[WS_CTXT + (size_t)(h*64 + tid)*16 + b] = v;   // transposed
            }
        }
        ++bno; gridbar(cnt, sense, s0 + bno);

        // ================= P2: GRU gates + finalize (blocks 0..31) =======
        if (blk < 32) {
            int cb = blk;
            float* xs   = (float*)s_raw;                  // 512*20 = 40 KB
            float* part = xs + 512*20;                    // 8*256
            float* gacc = part + 8*256;                   // 6*256

            {   // stage ctx^T -> xs [k][20]
                const float4* s4 = (const float4*)(ws + WS_CTXT);
                #pragma unroll
                for (int j = 0; j < 4; ++j) {
                    int i = tid + 512*j;
                    float4 v = s4[i];
                    int k = i >> 2, qo = i & 3;
                    *(float4*)(xs + k*20 + qo*4) = v;
                }
            }
            if (tid < 64) {   // sc output: 64 of 2048 (b,l) per block
                int e = cb*64 + tid;
                int b = e >> 7, l = e & 127;
                float s = 0.f;
                #pragma unroll
                for (int hq = 0; hq < NH; ++hq)
                    s += ws[WS_P + (size_t)(b*NH + hq)*LL + l];
                out[OUT_SC_OFF + ((size_t)t*BB + b)*LL + l] =
                    (t < olen[b]) ? s*0.125f : 0.f;
            }
            __syncthreads();

            int c4 = tid & 3, b4 = (tid >> 2) & 3, kc = tid >> 4;
            int wv = tid >> 6;
            for (int g = 0; g < 6; ++g) {
                const float* W = (g < 3) ? Wih : Whh;
                int gg = (g < 3) ? g : g - 3;
                const float* wp = W + (size_t)kc*(3*HH) + gg*HH + cb*16 + c4*4;
                float acc[4][4];
                #pragma unroll
                for (int i = 0; i < 4; ++i) { acc[i][0]=0.f; acc[i][1]=0.f; acc[i][2]=0.f; acc[i][3]=0.f; }
                if (g < 3) {
                    const float* xp = xs + kc*20 + b4*4;
                    #pragma unroll 8
                    for (int i = 0; i < 16; ++i) {
                        float4 w4 = *(const float4*)wp;
                        float4 x4 = *(const float4*)xp;
                        wp += (size_t)32*(3*HH);
                        xp += 32*20;
                        acc[0][0] += x4.x*w4.x; acc[0][1] += x4.x*w4.y; acc[0][2] += x4.x*w4.z; acc[0][3] += x4.x*w4.w;
                        acc[1][0] += x4.y*w4.x; acc[1][1] += x4.y*w4.y; acc[1][2] += x4.y*w4.z; acc[1][3] += x4.y*w4.w;
                        acc[2][0] += x4.z*w4.x; acc[2][1] += x4.z*w4.y; acc[2][2] += x4.z*w4.z; acc[2][3] += x4.z*w4.w;
                        acc[3][0] += x4.w*w4.x; acc[3][1] += x4.w*w4.y; acc[3][2] += x4.w*w4.z; acc[3][3] += x4.w*w4.w;
                    }
                } else {
                    const float* xp = hs_prev + kc*16 + b4*4;
                    #pragma unroll 8
                    for (int i = 0; i < 16; ++i) {
                        float4 w4 = *(const float4*)wp;
                        float4 x4 = *(const float4*)xp;
                        wp += (size_t)32*(3*HH);
                        xp += 32*16;
                        acc[0][0] += x4.x*w4.x; acc[0][1] += x4.x*w4.y; acc[0][2] += x4.x*w4.z; acc[0][3] += x4.x*w4.w;
                        acc[1][0] += x4.y*w4.x; acc[1][1] += x4.y*w4.y; acc[1][2] += x4.y*w4.z; acc[1][3] += x4.y*w4.w;
                        acc[2][0] += x4.z*w4.x; acc[2][1] += x4.z*w4.y; acc[2][2] += x4.z*w4.z; acc[2][3] += x4.z*w4.w;
                        acc[3][0] += x4.w*w4.x; acc[3][1] += x4.w*w4.y; acc[3][2] += x4.w*w4.z; acc[3][3] += x4.w*w4.w;
                    }
                }
                #pragma unroll
                for (int bi = 0; bi < 4; ++bi)
                    #pragma unroll
                    for (int ci = 0; ci < 4; ++ci) {
                        float v = acc[bi][ci];
                        v += __shfl_xor(v, 16);
                        v += __shfl_xor(v, 32);
                        acc[bi][ci] = v;
                    }
                if ((tid & 48) == 0) {
                    #pragma unroll
                    for (int bi = 0; bi < 4; ++bi)
                        *(float4*)(part + wv*256 + (b4*4+bi)*16 + c4*4) =
                            make_float4(acc[bi][0], acc[bi][1], acc[bi][2], acc[bi][3]);
                }
                __syncthreads();
                if (tid < 256) {
                    int b = tid >> 4, c = tid & 15;
                    float s = 0.f;
                    #pragma unroll
                    for (int w = 0; w < 8; ++w) s += part[w*256 + b*16 + c];
                    gacc[g*256 + b*16 + c] = s;
                }
                __syncthreads();
            }

            if (tid < 256) {   // finalize
                int b = tid >> 4, c = tid & 15;
                int col = cb*16 + c;
                float gir = gacc[0*256 + b*16 + c] + bih[col];
                float giz = gacc[1*256 + b*16 + c] + bih[HH + col];
                float gin = gacc[2*256 + b*16 + c] + bih[2*HH + col];
                float ghr = gacc[3*256 + b*16 + c] + bhh[col];
                float ghz = gacc[4*256 + b*16 + c] + bhh[HH + col];
                float ghn = gacc[5*256 + b*16 + c] + bhh[2*HH + col];
                float r = 1.f/(1.f + __expf(-(gir + ghr)));
                float z = 1.f/(1.f + __expf(-(giz + ghz)));
                float xn = gin + r*ghn;
                float n = 1.f - 2.f/(__expf(2.f*xn) + 1.f);
                float hprev = hs_prev[col*16 + b];
                float hnew = (1.f - z)*n + z*hprev;
                hs_new[col*16 + b] = hnew;                      // carry [k][b]
                out[OUT_HID_OFF + ((size_t)t*BB + b)*HH + col] =
                    (t < olen[b]) ? hnew : 0.f;
            }
        }
        ++bno; gridbar(cnt, sense, s0 + bno);

        // ================= P3: logits + argmax (all 250 blocks) ==========
        {
            float* hs = (float*)s_raw;                    // 512*20 = 40 KB
            unsigned long long* am = (unsigned long long*)(s_raw + 40960); // 16*32
            int colbase = blk * 64;

            {   // stage h_new [k][b] -> hs [k][20]
                const float4* s4 = (const float4*)hs_new;
                #pragma unroll
                for (int j = 0; j < 4; ++j) {
                    int i = tid + 512*j;
                    float4 v = s4[i];
                    int k = i >> 2, qo = i & 3;
                    *(float4*)(hs + k*20 + qo*4) = v;
                }
            }
            __syncthreads();

            int c4 = tid & 15, kc = tid >> 4;
            float acc[16][4];
            #pragma unroll
            for (int bi = 0; bi < 16; ++bi) { acc[bi][0]=0.f; acc[bi][1]=0.f; acc[bi][2]=0.f; acc[bi][3]=0.f; }
            const float* wp = Wf + (size_t)kc*VV + colbase + c4*4;
            const float* hp = hs + kc*20;
            #pragma unroll 8
            for (int i = 0; i < 16; ++i) {       // k = kc + 32*i
                float4 w4 = *(const float4*)wp;
                float4 h0 = *(const float4*)(hp);
                float4 h1 = *(const float4*)(hp + 4);
                float4 h2 = *(const float4*)(hp + 8);
                float4 h3 = *(const float4*)(hp + 12);
                wp += (size_t)32 * VV;
                hp += 32 * 20;
                #define LACC(bi, hv) acc[bi][0] += (hv)*w4.x; acc[bi][1] += (hv)*w4.y; \
                                     acc[bi][2] += (hv)*w4.z; acc[bi][3] += (hv)*w4.w;
                LACC(0,h0.x)  LACC(1,h0.y)  LACC(2,h0.z)  LACC(3,h0.w)
                LACC(4,h1.x)  LACC(5,h1.y)  LACC(6,h1.z)  LACC(7,h1.w)
                LACC(8,h2.x)  LACC(9,h2.y)  LACC(10,h2.z) LACC(11,h2.w)
                LACC(12,h3.x) LACC(13,h3.y) LACC(14,h3.z) LACC(15,h3.w)
                #undef LACC
            }
            #pragma unroll
            for (int bi = 0; bi < 16; ++bi)
                #pragma unroll
                for (int ci = 0; ci < 4; ++ci) {
                    float v = acc[bi][ci];
                    v += __shfl_xor(v, 16);
                    v += __shfl_xor(v, 32);
                    acc[bi][ci] = v;
                }
            __syncthreads();                 // hs reads done; reuse as red
            float* red = (float*)s_raw;      // 8 waves * 1024
            int wv = tid >> 6;
            if ((tid & 48) == 0) {
                #pragma unroll
                for (int bi = 0; bi < 16; ++bi)
                    *(float4*)(red + wv*1024 + bi*64 + c4*4) =
                        make_float4(acc[bi][0], acc[bi][1], acc[bi][2], acc[bi][3]);
            }
            __syncthreads();

            {   // final: 1024 outputs, 2 per thread
                int b = tid >> 5, cp = (tid & 31) * 2;
                float2 bf2 = *(const float2*)(bf + colbase + cp);
                float v0 = bf2.x, v1 = bf2.y;
                #pragma unroll
                for (int w = 0; w < 8; ++w) {
                    v0 += red[w*1024 + b*64 + cp];
                    v1 += red[w*1024 + b*64 + cp + 1];
                }
                bool active = t < olen[b];
                float2 ov; ov.x = active ? v0 : 0.f; ov.y = active ? v1 : 0.f;
                *(float2*)(out + ((size_t)t*BB + b)*VV + colbase + cp) = ov;

                unsigned u0 = __float_as_uint(v0);
                u0 = (u0 & 0x80000000u) ? ~u0 : (u0 | 0x80000000u);
                unsigned u1 = __float_as_uint(v1);
                u1 = (u1 & 0x80000000u) ? ~u1 : (u1 | 0x80000000u);
                unsigned long long e0 = ((unsigned long long)u0 << 32)
                    | (unsigned long long)(0xFFFFFFFFu - (unsigned)(colbase + cp));
                unsigned long long e1 = ((unsigned long long)u1 << 32)
                    | (unsigned long long)(0xFFFFFFFFu - (unsigned)(colbase + cp + 1));
                am[b*32 + (tid & 31)] = e0 > e1 ? e0 : e1;
            }
            __syncthreads();
            if (tid < BB) {
                unsigned long long m = 0ull;
                #pragma unroll
                for (int i = 0; i < 32; ++i) {
                    unsigned long long v = am[tid*32 + i];
                    m = v > m ? v : m;
                }
                atomicMax(&slots[(size_t)(t+1)*BB + tid], m);
            }
        }
        if (t < TT - 1) { ++bno; gridbar(cnt, sense, s0 + bno); }
    }
}

extern "C" void kernel_launch(void* const* d_in, const int* in_sizes, int n_in,
                              void* d_out, int out_size, void* d_ws, size_t ws_size,
                              hipStream_t stream) {
    const float* mem = (const float*)d_in[0];
    const float* emb = (const float*)d_in[1];
    const float* Wq  = (const float*)d_in[2];
    const float* bq  = (const float*)d_in[3];
    const float* Wk  = (const float*)d_in[4];
    const float* bk  = (const float*)d_in[5];
    const float* Wv  = (const float*)d_in[6];
    const float* bv  = (const float*)d_in[7];
    const float* Wih = (const float*)d_in[8];
    const float* bih = (const float*)d_in[9];
    const float* Whh = (const float*)d_in[10];
    const float* bhh = (const float*)d_in[11];
    const float* Wf  = (const float*)d_in[12];
    const float* bf  = (const float*)d_in[13];
    const int* olen  = (const int*)d_in[14];
    float* out = (float*)d_out;
    float* ws  = (float*)d_ws;

    hipLaunchKernelGGL(kv_kernel, dim3(2048), dim3(256), 0, stream, mem, Wk, bk, Wv, bv, ws);
    hipLaunchKernelGGL(mega_kernel, dim3(NBLK), dim3(512), 0, stream,
                       emb, Wq, bq, Wih, bih, Whh, bhh, Wf, bf, olen, ws, out);
}

// Round 6
// 2623.799 us; speedup vs baseline: 1.2852x; 1.2852x over previous
//
#include <hip/hip_runtime.h>

#define LL 128      // memory length
#define BB 16       // batch
#define HH 512      // hidden
#define VV 16000    // vocab
#define TT 32       // steps
#define NH 8        // heads
#define DK 64      // head dim
#define NBLK 250    // mega grid (1 block/CU, co-resident)

// workspace layout (float offsets)
#define WS_K 0
#define WS_V (LL*BB*HH)                     // K,V: rows l*BB+b, 512 cols
#define WS_CTXT (2*LL*BB*HH)                // ctx transposed [k][b] (512*16)
#define WS_HS0 (WS_CTXT + BB*HH)            // h ping [k][b]
#define WS_HS1 (WS_HS0 + BB*HH)             // h pong [k][b]
#define WS_P   (WS_HS1 + BB*HH)             // p[b][h][128]
#define WS_SLOTS_F (WS_P + BB*NH*LL)        // (TT+1)*BB u64 argmax slots
#define WS_BAR (WS_SLOTS_F + 2*(TT+1)*BB + 16)  // cnt, sense

#define OUT_HID_OFF ((size_t)TT*BB*VV)
#define OUT_SC_OFF  (OUT_HID_OFF + (size_t)TT*BB*HH)

// ---- coherent (L2-bypassing, agent-scope relaxed atomic) access helpers ----
// All inter-block communication inside mega goes through these; weights use
// normal cached loads and are NEVER invalidated (no fences anywhere).
__device__ __forceinline__ float ld_coh1(const float* p) {
    unsigned v = __hip_atomic_load((const unsigned*)p, __ATOMIC_RELAXED,
                                   __HIP_MEMORY_SCOPE_AGENT);
    return __uint_as_float(v);
}
__device__ __forceinline__ void st_coh1(float* p, float a) {
    __hip_atomic_store((unsigned*)p, __float_as_uint(a), __ATOMIC_RELAXED,
                       __HIP_MEMORY_SCOPE_AGENT);
}
__device__ __forceinline__ float2 ld_coh2(const float* p) {
    unsigned long long v = __hip_atomic_load((const unsigned long long*)p,
                           __ATOMIC_RELAXED, __HIP_MEMORY_SCOPE_AGENT);
    float2 r; r.x = __uint_as_float((unsigned)v);
    r.y = __uint_as_float((unsigned)(v >> 32));
    return r;
}
__device__ __forceinline__ float4 ld_coh4(const float* p) {
    float2 a = ld_coh2(p), b = ld_coh2(p + 2);
    float4 r; r.x = a.x; r.y = a.y; r.z = b.x; r.w = b.y;
    return r;
}

// ---------------- kv projection + per-call init ----------------
__global__ __launch_bounds__(256) void kv_kernel(const float* __restrict__ mem,
        const float* __restrict__ Wk, const float* __restrict__ bk,
        const float* __restrict__ Wv, const float* __restrict__ bv,
        float* __restrict__ ws) {
    int blk = blockIdx.x;
    int rg = blk >> 4, ct = blk & 15;
    int isV = ct >= 8;
    int colbase = (ct & 7) * 64;
    const float* W = isV ? Wv : Wk;
    const float* bias = isV ? bv : bk;
    float* outp = ws + (isV ? WS_V : WS_K);
    int rowbase = rg * 16;
    int tid = threadIdx.x;
    __shared__ float As[16*516];

    {   // stage 16x512 A rows into padded LDS
        const float4* srcp = (const float4*)(mem + (size_t)rowbase*512);
        #pragma unroll
        for (int j = 0; j < 8; ++j) {
            int i = tid + 256*j;
            float4 v = srcp[i];
            int row = i >> 7, c4i = i & 127;
            *(float4*)(As + row*516 + c4i*4) = v;
        }
    }
    if (blk == 0) {
        for (int i = tid; i < BB*HH; i += 256) ws[WS_HS0 + i] = 0.f;   // h(-1)=0
        unsigned long long* slots = (unsigned long long*)(ws + WS_SLOTS_F);
        for (int i = tid; i < (TT+1)*BB; i += 256)
            slots[i] = (i < BB) ? 0xFFFFFFFFull : 0ull;   // step0 argmax(zeros)=0
        if (tid == 0) *(unsigned*)(ws + WS_BAR) = 0u;     // barrier cnt = 0
    }
    __syncthreads();

    int cq = tid & 15;
    int rq4 = (tid >> 4) & 3;
    int kq = tid >> 6;
    float acc[4][4];
    #pragma unroll
    for (int i = 0; i < 4; ++i) { acc[i][0]=0.f; acc[i][1]=0.f; acc[i][2]=0.f; acc[i][3]=0.f; }
    const float* wp = W + colbase + cq*4;
    for (int k4 = kq*32; k4 < kq*32 + 32; ++k4) {
        float4 a0 = *(const float4*)(As + (rq4*4+0)*516 + k4*4);
        float4 a1 = *(const float4*)(As + (rq4*4+1)*516 + k4*4);
        float4 a2 = *(const float4*)(As + (rq4*4+2)*516 + k4*4);
        float4 a3 = *(const float4*)(As + (rq4*4+3)*516 + k4*4);
        const float* wrow = wp + (size_t)(4*k4)*512;
        float4 w0 = *(const float4*)(wrow);
        float4 w1 = *(const float4*)(wrow + 512);
        float4 w2 = *(const float4*)(wrow + 1024);
        float4 w3 = *(const float4*)(wrow + 1536);
        #define KV_FMA(ri, A) \
            acc[ri][0] += A.x*w0.x + A.y*w1.x + A.z*w2.x + A.w*w3.x; \
            acc[ri][1] += A.x*w0.y + A.y*w1.y + A.z*w2.y + A.w*w3.y; \
            acc[ri][2] += A.x*w0.z + A.y*w1.z + A.z*w2.z + A.w*w3.z; \
            acc[ri][3] += A.x*w0.w + A.y*w1.w + A.z*w2.w + A.w*w3.w;
        KV_FMA(0, a0) KV_FMA(1, a1) KV_FMA(2, a2) KV_FMA(3, a3)
        #undef KV_FMA
    }
    __syncthreads();
    float* red = As;
    #pragma unroll
    for (int ri = 0; ri < 4; ++ri)
        *(float4*)(red + ri*1024 + tid*4) =
            make_float4(acc[ri][0], acc[ri][1], acc[ri][2], acc[ri][3]);
    __syncthreads();
    {
        int c4 = tid & 15, row = tid >> 4;
        int rq = row >> 2, ri = row & 3;
        float4 b4v = *(const float4*)(bias + colbase + c4*4);
        float o[4] = {b4v.x, b4v.y, b4v.z, b4v.w};
        #pragma unroll
        for (int kq2 = 0; kq2 < 4; ++kq2) {
            const float* pr = red + ri*1024 + (kq2*64 + rq*16 + c4)*4;
            o[0] += pr[0]; o[1] += pr[1]; o[2] += pr[2]; o[3] += pr[3];
        }
        *(float4*)(outp + (size_t)(rowbase + row)*512 + colbase + c4*4) =
            make_float4(o[0], o[1], o[2], o[3]);
    }
}

// ---------------- grid barrier: NO fences (no L2 writeback/invalidate). ----
// __syncthreads() before arrival drains all waves' vmem (compiler emits full
// waitcnt before s_barrier), so coherent stores are at the coherence point
// before the arrive atomic. Poll is a relaxed agent load (sc1, bypasses L2).
__device__ __forceinline__ void gridbar(unsigned* cnt, unsigned* sense,
                                        unsigned target) {
    __syncthreads();
    if (threadIdx.x == 0) {
        unsigned old = __hip_atomic_fetch_add(cnt, 1u, __ATOMIC_RELAXED,
                                              __HIP_MEMORY_SCOPE_AGENT);
        if (old == (unsigned)NBLK - 1u) {
            __hip_atomic_store(cnt, 0u, __ATOMIC_RELAXED, __HIP_MEMORY_SCOPE_AGENT);
            __builtin_amdgcn_s_waitcnt(0);   // cnt reset visible before sense bump
            __hip_atomic_fetch_add(sense, 1u, __ATOMIC_RELAXED,
                                   __HIP_MEMORY_SCOPE_AGENT);
        } else {
            while ((int)(__hip_atomic_load(sense, __ATOMIC_RELAXED,
                         __HIP_MEMORY_SCOPE_AGENT) - target) < 0)
                __builtin_amdgcn_s_sleep(2);
        }
    }
    __syncthreads();
}

// ---------------- mega kernel: all 32 steps ----------------
__global__ __launch_bounds__(512) void mega_kernel(
        const float* __restrict__ emb, const float* __restrict__ Wq,
        const float* __restrict__ bq,
        const float* __restrict__ Wih, const float* __restrict__ bih,
        const float* __restrict__ Whh, const float* __restrict__ bhh,
        const float* __restrict__ Wf,  const float* __restrict__ bf,
        const int* __restrict__ olen, float* __restrict__ ws,
        float* __restrict__ out) {
    __shared__ __align__(16) char s_raw[57344];
    int blk = blockIdx.x, tid = threadIdx.x;
    unsigned* cnt = (unsigned*)(ws + WS_BAR);
    unsigned* sense = cnt + 1;
    unsigned s0 = 0;
    if (tid == 0)
        s0 = __hip_atomic_load(sense, __ATOMIC_RELAXED, __HIP_MEMORY_SCOPE_AGENT);
    unsigned bno = 0;
    unsigned long long* slots = (unsigned long long*)(ws + WS_SLOTS_F);

    for (int t = 0; t < TT; ++t) {
        const float* hs_prev = ws + ((t & 1) ? WS_HS1 : WS_HS0);
        float* hs_new = ws + ((t & 1) ? WS_HS0 : WS_HS1);

        // ================= P1: attention (blocks 0..127) =================
        if (blk < 128) {
            int b = blk >> 3, h = blk & 7;
            float* q     = (float*)s_raw;                 // 1024
            float* part  = q + 1024;                      // 16*64
            float* qh    = part + 1024;                   // 64
            float* sp    = qh + 64;                       // 4*128
            float* p     = sp + 512;                      // 128
            float* cpart = p + 128;                       // 8*64

            unsigned long long slot = __hip_atomic_load(&slots[t*BB + b],
                __ATOMIC_RELAXED, __HIP_MEMORY_SCOPE_AGENT);
            unsigned idx = 0xFFFFFFFFu - (unsigned)(slot & 0xFFFFFFFFull);
            q[tid] = emb[(size_t)idx*HH + tid];           // cached read-only
            q[HH + tid] = ld_coh1(hs_prev + tid*16 + b);  // coherent
            __syncthreads();

            {   // qproj: c2 = tid&31 (2 cols), kc = tid>>5 (16 slices of 32 k)
                int c2 = tid & 31, kc = tid >> 5;
                const float* wp = Wq + (size_t)(kc*64)*HH + h*64 + c2*2;
                const float* qp = q + kc*64;
                float a0 = 0.f, a1 = 0.f;
                #pragma unroll 8
                for (int kk = 0; kk < 64; ++kk) {
                    float x = qp[kk];
                    float2 w2 = *(const float2*)(wp + (size_t)kk*HH);
                    a0 += x*w2.x; a1 += x*w2.y;
                }
                part[kc*64 + c2*2]     = a0;
                part[kc*64 + c2*2 + 1] = a1;
            }
            __syncthreads();
            if (tid < 64) {
                float s = bq[h*64 + tid];
                #pragma unroll
                for (int kc = 0; kc < 16; ++kc) s += part[kc*64 + tid];
                qh[tid] = s;
            }
            __syncthreads();

            {   // scores: l = tid&127, jh = tid>>7 (0..3, 16 k each)
                int l = tid & 127, jh = tid >> 7;
                const float4* kr = (const float4*)(ws + WS_K +
                                   ((size_t)(l*BB + b))*HH + h*DK) + jh*4;
                const float4* q4 = (const float4*)qh + jh*4;
                float acc = 0.f;
                #pragma unroll
                for (int j = 0; j < 4; ++j) {
                    float4 kv = kr[j], qq = q4[j];
                    acc += qq.x*kv.x + qq.y*kv.y + qq.z*kv.z + qq.w*kv.w;
                }
                sp[jh*128 + l] = acc;
            }
            __syncthreads();

            if (tid < 64) {   // softmax over 128 (wave 0)
                float s0v = (sp[tid]    + sp[128+tid]    + sp[256+tid]    + sp[384+tid])    * 0.125f;
                float s1v = (sp[64+tid] + sp[128+64+tid] + sp[256+64+tid] + sp[384+64+tid]) * 0.125f;
                float m = fmaxf(s0v, s1v);
                #pragma unroll
                for (int off = 32; off; off >>= 1) m = fmaxf(m, __shfl_xor(m, off));
                float e0 = __expf(s0v - m), e1 = __expf(s1v - m);
                float sum = e0 + e1;
                #pragma unroll
                for (int off = 32; off; off >>= 1) sum += __shfl_xor(sum, off);
                float inv = 1.f / sum;
                p[tid]      = e0 * inv;
                p[64 + tid] = e1 * inv;
            }
            __syncthreads();
            if (tid < 128)
                st_coh1(ws + WS_P + (size_t)(b*NH + h)*LL + tid, p[tid]);

            {   // ctx: c = tid&63, lc = tid>>6 (8 slices of 16 l)
                int c = tid & 63, lc = tid >> 6;
                const float* Vp = ws + WS_V + h*DK + c;
                float acc = 0.f;
                #pragma unroll 8
                for (int li = 0; li < 16; ++li) {
                    int l = lc*16 + li;
                    acc += p[l] * Vp[(size_t)(l*BB + b)*HH];
                }
                cpart[lc*64 + c] = acc;
            }
            __syncthreads();
            if (tid < 64) {
                float v = cpart[tid];
                #pragma unroll
                for (int lc = 1; lc < 8; ++lc) v += cpart[lc*64 + tid];
                st_coh1(ws + WS_CTXT + (size_t)(h*64 + tid)*16 + b, v);
            }
        }
        ++bno; gridbar(cnt, sense, s0 + bno);

        // ================= P2: GRU gates + finalize (blocks 0..31) =======
        if (blk < 32) {
            int cb = blk;
            float* part = (float*)s_raw;                  // 8*256
            float* gacc = part + 8*256;                   // 6*256

            if (tid < 64) {   // sc output: 64 of 2048 (b,l) per block
                int e = cb*64 + tid;
                int b = e >> 7, l = e & 127;
                float s = 0.f;
                #pragma unroll
                for (int hq = 0; hq < NH; ++hq)
                    s += ld_coh1(ws + WS_P + (size_t)(b*NH + hq)*LL + l);
                out[OUT_SC_OFF + ((size_t)t*BB + b)*LL + l] =
                    (t < olen[b]) ? s*0.125f : 0.f;
            }

            int c4 = tid & 3, b4 = (tid >> 2) & 3, kc = tid >> 4;
            int wv = tid >> 6;
            float4 xv[16];
            #pragma unroll
            for (int i = 0; i < 16; ++i)
                xv[i] = ld_coh4(ws + WS_CTXT + (size_t)(kc + 32*i)*16 + b4*4);

            for (int g = 0; g < 6; ++g) {
                if (g == 3) {
                    #pragma unroll
                    for (int i = 0; i < 16; ++i)
                        xv[i] = ld_coh4(hs_prev + (size_t)(kc + 32*i)*16 + b4*4);
                }
                const float* W = (g < 3) ? Wih : Whh;
                int gg = (g < 3) ? g : g - 3;
                const float* wp = W + (size_t)kc*(3*HH) + gg*HH + cb*16 + c4*4;
                float acc[4][4];
                #pragma unroll
                for (int i = 0; i < 4; ++i) { acc[i][0]=0.f; acc[i][1]=0.f; acc[i][2]=0.f; acc[i][3]=0.f; }
                #pragma unroll
                for (int i = 0; i < 16; ++i) {     // k = kc + 32*i
                    float4 w4 = *(const float4*)wp;
                    wp += (size_t)32*(3*HH);
                    float4 x4 = xv[i];
                    acc[0][0] += x4.x*w4.x; acc[0][1] += x4.x*w4.y; acc[0][2] += x4.x*w4.z; acc[0][3] += x4.x*w4.w;
                    acc[1][0] += x4.y*w4.x; acc[1][1] += x4.y*w4.y; acc[1][2] += x4.y*w4.z; acc[1][3] += x4.y*w4.w;
                    acc[2][0] += x4.z*w4.x; acc[2][1] += x4.z*w4.y; acc[2][2] += x4.z*w4.z; acc[2][3] += x4.z*w4.w;
                    acc[3][0] += x4.w*w4.x; acc[3][1] += x4.w*w4.y; acc[3][2] += x4.w*w4.z; acc[3][3] += x4.w*w4.w;
                }
                #pragma unroll
                for (int bi = 0; bi < 4; ++bi)
                    #pragma unroll
                    for (int ci = 0; ci < 4; ++ci) {
                        float v = acc[bi][ci];
                        v += __shfl_xor(v, 16);
                        v += __shfl_xor(v, 32);
                        acc[bi][ci] = v;
                    }
                if ((tid & 48) == 0) {
                    #pragma unroll
                    for (int bi = 0; bi < 4; ++bi)
                        *(float4*)(part + wv*256 + (b4*4+bi)*16 + c4*4) =
                            make_float4(acc[bi][0], acc[bi][1], acc[bi][2], acc[bi][3]);
                }
                __syncthreads();
                if (tid < 256) {
                    int b = tid >> 4, c = tid & 15;
                    float s = 0.f;
                    #pragma unroll
                    for (int w = 0; w < 8; ++w) s += part[w*256 + b*16 + c];
                    gacc[g*256 + b*16 + c] = s;
                }
                __syncthreads();
            }

            if (tid < 256) {   // finalize
                int b = tid >> 4, c = tid & 15;
                int col = cb*16 + c;
                float gir = gacc[0*256 + b*16 + c] + bih[col];
                float giz = gacc[1*256 + b*16 + c] + bih[HH + col];
                float gin = gacc[2*256 + b*16 + c] + bih[2*HH + col];
                float ghr = gacc[3*256 + b*16 + c] + bhh[col];
                float ghz = gacc[4*256 + b*16 + c] + bhh[HH + col];
                float ghn = gacc[5*256 + b*16 + c] + bhh[2*HH + col];
                float r = 1.f/(1.f + __expf(-(gir + ghr)));
                float z = 1.f/(1.f + __expf(-(giz + ghz)));
                float xn = gin + r*ghn;
                float n = 1.f - 2.f/(__expf(2.f*xn) + 1.f);
                float hprev = ld_coh1(hs_prev + col*16 + b);
                float hnew = (1.f - z)*n + z*hprev;
                st_coh1(hs_new + col*16 + b, hnew);             // carry [k][b]
                out[OUT_HID_OFF + ((size_t)t*BB + b)*HH + col] =
                    (t < olen[b]) ? hnew : 0.f;
            }
        } else if (t == 0) {
            // idle blocks warm their Wf slice into this XCD's L2 (step 0 only)
            int colbase = blk * 64;
            const float* wp = Wf + colbase + (tid & 15)*4;
            float4 s4 = make_float4(0.f, 0.f, 0.f, 0.f);
            #pragma unroll 4
            for (int k = tid >> 4; k < HH; k += 32) {
                float4 w = *(const float4*)(wp + (size_t)k*VV);
                s4.x += w.x; s4.y += w.y; s4.z += w.z; s4.w += w.w;
            }
            asm volatile("" :: "v"(s4.x), "v"(s4.y), "v"(s4.z), "v"(s4.w));
        }
        ++bno; gridbar(cnt, sense, s0 + bno);

        // ================= P3: logits + argmax (all 250 blocks) ==========
        {
            float* hs = (float*)s_raw;                    // 512*20 = 40 KB
            unsigned long long* am = (unsigned long long*)(s_raw + 40960);
            int colbase = blk * 64;

            {   // stage h_new [k][b] -> hs [k][20]  (coherent loads)
                #pragma unroll
                for (int j = 0; j < 4; ++j) {
                    int i = tid + 512*j;                  // 2048 float4s
                    float4 v = ld_coh4(hs_new + (size_t)i*4);
                    int k = i >> 2, qo = i & 3;
                    *(float4*)(hs + k*20 + qo*4) = v;
                }
            }
            __syncthreads();

            int c4 = tid & 15, kc = tid >> 4;
            float acc[16][4];
            #pragma unroll
            for (int bi = 0; bi < 16; ++bi) { acc[bi][0]=0.f; acc[bi][1]=0.f; acc[bi][2]=0.f; acc[bi][3]=0.f; }
            const float* wp = Wf + (size_t)kc*VV + colbase + c4*4;
            const float* hp = hs + kc*20;
            #pragma unroll 8
            for (int i = 0; i < 16; ++i) {       // k = kc + 32*i
                float4 w4 = *(const float4*)wp;
                float4 h0 = *(const float4*)(hp);
                float4 h1 = *(const float4*)(hp + 4);
                float4 h2 = *(const float4*)(hp + 8);
                float4 h3 = *(const float4*)(hp + 12);
                wp += (size_t)32 * VV;
                hp += 32 * 20;
                #define LACC(bi, hv) acc[bi][0] += (hv)*w4.x; acc[bi][1] += (hv)*w4.y; \
                                     acc[bi][2] += (hv)*w4.z; acc[bi][3] += (hv)*w4.w;
                LACC(0,h0.x)  LACC(1,h0.y)  LACC(2,h0.z)  LACC(3,h0.w)
                LACC(4,h1.x)  LACC(5,h1.y)  LACC(6,h1.z)  LACC(7,h1.w)
                LACC(8,h2.x)  LACC(9,h2.y)  LACC(10,h2.z) LACC(11,h2.w)
                LACC(12,h3.x) LACC(13,h3.y) LACC(14,h3.z) LACC(15,h3.w)
                #undef LACC
            }
            #pragma unroll
            for (int bi = 0; bi < 16; ++bi)
                #pragma unroll
                for (int ci = 0; ci < 4; ++ci) {
                    float v = acc[bi][ci];
                    v += __shfl_xor(v, 16);
                    v += __shfl_xor(v, 32);
                    acc[bi][ci] = v;
                }
            __syncthreads();                 // hs reads done; reuse as red
            float* red = (float*)s_raw;      // 8 waves * 1024
            int wv = tid >> 6;
            if ((tid & 48) == 0) {
                #pragma unroll
                for (int bi = 0; bi < 16; ++bi)
                    *(float4*)(red + wv*1024 + bi*64 + c4*4) =
                        make_float4(acc[bi][0], acc[bi][1], acc[bi][2], acc[bi][3]);
            }
            __syncthreads();

            {   // final: 1024 outputs, 2 per thread
                int b = tid >> 5, cp = (tid & 31) * 2;
                float2 bf2 = *(const float2*)(bf + colbase + cp);
                float v0 = bf2.x, v1 = bf2.y;
                #pragma unroll
                for (int w = 0; w < 8; ++w) {
                    v0 += red[w*1024 + b*64 + cp];
                    v1 += red[w*1024 + b*64 + cp + 1];
                }
                bool active = t < olen[b];
                float2 ov; ov.x = active ? v0 : 0.f; ov.y = active ? v1 : 0.f;
                *(float2*)(out + ((size_t)t*BB + b)*VV + colbase + cp) = ov;

                unsigned u0 = __float_as_uint(v0);
                u0 = (u0 & 0x80000000u) ? ~u0 : (u0 | 0x80000000u);
                unsigned u1 = __float_as_uint(v1);
                u1 = (u1 & 0x80000000u) ? ~u1 : (u1 | 0x80000000u);
                unsigned long long e0 = ((unsigned long long)u0 << 32)
                    | (unsigned long long)(0xFFFFFFFFu - (unsigned)(colbase + cp));
                unsigned long long e1 = ((unsigned long long)u1 << 32)
                    | (unsigned long long)(0xFFFFFFFFu - (unsigned)(colbase + cp + 1));
                am[b*32 + (tid & 31)] = e0 > e1 ? e0 : e1;
            }
            __syncthreads();
            if (tid < BB) {
                unsigned long long m = 0ull;
                #pragma unroll
                for (int i = 0; i < 32; ++i) {
                    unsigned long long v = am[tid*32 + i];
                    m = v > m ? v : m;
                }
                atomicMax(&slots[(size_t)(t+1)*BB + tid], m);
            }
        }
        if (t < TT - 1) { ++bno; gridbar(cnt, sense, s0 + bno); }
    }
}

extern "C" void kernel_launch(void* const* d_in, const int* in_sizes, int n_in,
                              void* d_out, int out_size, void* d_ws, size_t ws_size,
                              hipStream_t stream) {
    const float* mem = (const float*)d_in[0];
    const float* emb = (const float*)d_in[1];
    const float* Wq  = (const float*)d_in[2];
    const float* bq  = (const float*)d_in[3];
    const float* Wk  = (const float*)d_in[4];
    const float* bk  = (const float*)d_in[5];
    const float* Wv  = (const float*)d_in[6];
    const float* bv  = (const float*)d_in[7];
    const float* Wih = (const float*)d_in[8];
    const float* bih = (const float*)d_in[9];
    const float* Whh = (const float*)d_in[10];
    const float* bhh = (const float*)d_in[11];
    const float* Wf  = (const float*)d_in[12];
    const float* bf  = (const float*)d_in[13];
    const int* olen  = (const int*)d_in[14];
    float* out = (float*)d_out;
    float* ws  = (float*)d_ws;

    hipLaunchKernelGGL(kv_kernel, dim3(2048), dim3(256), 0, stream, mem, Wk, bk, Wv, bv, ws);
    hipLaunchKernelGGL(mega_kernel, dim3(NBLK), dim3(512), 0, stream,
                       emb, Wq, bq, Wih, bih, Whh, bhh, Wf, bf, olen, ws, out);
}